// Round 4
// baseline (1518.778 us; speedup 1.0000x reference)
//
#include <hip/hip_runtime.h>
#include <hip/hip_bf16.h>

#define DD 32
#define TT 9
#define LL 24
#define HH 8
#define NPOS 216           // TT*LL
#define RPB_W 47           // 2*LL-1
#define ALPHA 0.9f

typedef __attribute__((ext_vector_type(8))) short short8x;
typedef __attribute__((ext_vector_type(4))) float float4x;

__device__ __forceinline__ float gelu_exact(float x) {
    return 0.5f * x * (1.0f + erff(x * 0.7071067811865476f));
}
__device__ __forceinline__ float sigmoidf_(float x) { return 1.0f / (1.0f + expf(-x)); }

__device__ __forceinline__ short f2b(float f) {
    union { float f; unsigned u; } x; x.f = f;
    unsigned r = x.u + 0x7fffu + ((x.u >> 16) & 1u);   // round-to-nearest-even
    return (short)(r >> 16);
}
__device__ __forceinline__ float b2f(short s) {
    union { unsigned u; float f; } x;
    x.u = ((unsigned)(unsigned short)s) << 16;
    return x.f;
}

// ws float layout: [0,1024) a32 ; [1024,1088) wl05=0.5*W_logit ; [1088,1472) rpm[8][48]
// [2048, 2048+B*32) spool (later overwritten with g*delta) ; then ssq (B*32)

// ---------------- K0: a32 + premixed 0.5*W_logit + premixed rel-pos bias ----------------
__global__ void k0_prep(const float* __restrict__ wcausal,
                        const float* __restrict__ w_logit,
                        const float* __restrict__ rpb,
                        float* __restrict__ ws) {
    __shared__ float A[DD][DD];
    __shared__ float rs[DD];
    int tid = threadIdx.x;              // 1024 threads
    int i = tid >> 5, j = tid & 31;
    float a = (i == j) ? 0.0f : log1pf(expf(wcausal[tid]));
    A[i][j] = a;
    __syncthreads();
    if (j == 0) {
        float s = 0.0f;
        for (int k = 0; k < DD; k++) s += A[i][k];
        rs[i] = ALPHA / (s + 1e-6f);
    }
    __syncthreads();
    ws[tid] = A[i][j] * rs[i];
    if (tid < 64) ws[1024 + tid] = 0.5f * w_logit[tid];
    if (tid < 384) {
        int H = tid / 48, r = tid % 48;
        float v = 0.0f;
        if (r < RPB_W) {
            for (int h = 0; h < HH; h++) v += w_logit[h * HH + H] * rpb[h * RPB_W + r];
        }
        ws[1088 + tid] = v;
    }
}

// ---------------- K1a: per-(b,c) sum / sum-of-squares (memory-bound) ----------------
__global__ __launch_bounds__(256) void k1a(const float* __restrict__ x,
                                           float* __restrict__ sp, float* __restrict__ sq) {
    int b = blockIdx.x, tid = threadIdx.x;
    int c = tid >> 3, r = tid & 7;
    const float4* x4 = (const float4*)(x + (size_t)b * (DD * NPOS) + (size_t)c * NPOS);
    float s = 0.0f, q = 0.0f;
    for (int k = r; k < 54; k += 8) {   // 54 float4 = 216 floats
        float4 v = x4[k];
        s += v.x + v.y + v.z + v.w;
        q += v.x * v.x + v.y * v.y + v.z * v.z + v.w * v.w;
    }
    for (int m = 1; m < 8; m <<= 1) { s += __shfl_xor(s, m); q += __shfl_xor(q, m); }
    if (r == 0) { sp[b * DD + c] = s; sq[b * DD + c] = q; }
}

// ---------------- K1b: one batch element per thread; full chain in registers ----------------
__global__ __launch_bounds__(64) void k1b(
    const float* __restrict__ ln_g, const float* __restrict__ ln_b,
    const float* __restrict__ rp_w1, const float* __restrict__ rp_b1,
    const float* __restrict__ rp_w2, const float* __restrict__ rp_b2,
    const float* __restrict__ mask_w, const float* __restrict__ mask_b,
    const float* __restrict__ val_w1, const float* __restrict__ val_b1,
    const float* __restrict__ val_w2, const float* __restrict__ val_b2,
    const float* __restrict__ fuse_gate, const float* __restrict__ ws,
    float* __restrict__ sp /* in: sums; out: g*delta */, const float* __restrict__ sq)
{
    __shared__ float W[6][1024];   // rp_w1, rp_w2, mask_w, val_w1, val_w2, a32
    __shared__ float V[7][32];     // ln_g, ln_b, rp_b1, rp_b2, mask_b, val_b1, val_b2
    int tid = threadIdx.x;
    for (int idx = tid; idx < 1024; idx += 64) {
        W[0][idx] = rp_w1[idx]; W[1][idx] = rp_w2[idx]; W[2][idx] = mask_w[idx];
        W[3][idx] = val_w1[idx]; W[4][idx] = val_w2[idx]; W[5][idx] = ws[idx];
    }
    if (tid < 32) {
        V[0][tid] = ln_g[tid]; V[1][tid] = ln_b[tid]; V[2][tid] = rp_b1[tid];
        V[3][tid] = rp_b2[tid]; V[4][tid] = mask_b[tid]; V[5][tid] = val_b1[tid];
        V[6][tid] = val_b2[tid];
    }
    __syncthreads();
    int b = blockIdx.x * 64 + tid;

    float pooled[32], scl[32];
    const float4* sp4 = (const float4*)(sp + (size_t)b * 32);
    const float4* sq4 = (const float4*)(sq + (size_t)b * 32);
    #pragma unroll
    for (int k = 0; k < 8; k++) {
        float4 sv = sp4[k], qv = sq4[k];
        float ss[4] = {sv.x, sv.y, sv.z, sv.w};
        float qq[4] = {qv.x, qv.y, qv.z, qv.w};
        #pragma unroll
        for (int m = 0; m < 4; m++) {
            int c = 4 * k + m;
            float p = ss[m] * (1.0f / NPOS);
            pooled[c] = p;
            float var1 = (qq[m] - (float)NPOS * p * p) * (1.0f / (NPOS - 1));
            scl[c] = fmaxf(sqrtf(fmaxf(var1, 0.0f)), 1e-3f);
        }
    }
    float mu = 0.0f;
    #pragma unroll
    for (int c = 0; c < 32; c++) mu += pooled[c];
    mu *= (1.0f / 32.0f);
    float vv = 0.0f;
    #pragma unroll
    for (int c = 0; c < 32; c++) { float d = pooled[c] - mu; vv += d * d; }
    vv *= (1.0f / 32.0f);
    float inv = rsqrtf(vv + 1e-5f);
    float pn[32];
    #pragma unroll
    for (int c = 0; c < 32; c++) pn[c] = (pooled[c] - mu) * inv * V[0][c] + V[1][c];

    float h1[32];
    #pragma unroll
    for (int i = 0; i < 32; i++) {
        float acc = V[2][i];
        #pragma unroll
        for (int j = 0; j < 32; j++) acc += pn[j] * W[0][i * 32 + j];
        h1[i] = gelu_exact(acc);
    }
    float pr[32];
    #pragma unroll
    for (int i = 0; i < 32; i++) {
        float acc = V[3][i];
        #pragma unroll
        for (int j = 0; j < 32; j++) acc += h1[j] * W[1][i * 32 + j];
        pr[i] = acc;
    }
    float g1[32];
    #pragma unroll
    for (int i = 0; i < 32; i++) {
        float acc = V[5][i];
        #pragma unroll
        for (int j = 0; j < 32; j++) acc += pr[j] * W[3][i * 32 + j];
        g1[i] = gelu_exact(acc);
    }
    float xd[32];
    #pragma unroll
    for (int i = 0; i < 32; i++) {
        float am = V[4][i];
        #pragma unroll
        for (int j = 0; j < 32; j++) am += pr[j] * W[2][i * 32 + j];
        float M = sigmoidf_(am);
        float av = V[6][i];
        #pragma unroll
        for (int j = 0; j < 32; j++) av += g1[j] * W[4][i * 32 + j];
        float v32 = tanhf(av) * scl[i] + pooled[i];
        xd[i] = (1.0f - M) * pooled[i] + M * v32;
    }
    float y[32];
    #pragma unroll
    for (int c = 0; c < 32; c++) y[c] = xd[c];
    for (int it = 0; it < 3; it++) {
        float ny[32];
        #pragma unroll
        for (int i = 0; i < 32; i++) {
            float acc = xd[i];
            #pragma unroll
            for (int j = 0; j < 32; j++) acc += y[j] * W[5][i * 32 + j];
            ny[i] = acc;
        }
        #pragma unroll
        for (int c = 0; c < 32; c++) y[c] = ny[c];
    }
    float g = sigmoidf_(fuse_gate[0]);
    float4* dout4 = (float4*)(sp + (size_t)b * 32);
    #pragma unroll
    for (int k = 0; k < 8; k++) {
        float4 o;
        o.x = g * (y[4 * k + 0] - pooled[4 * k + 0]);
        o.y = g * (y[4 * k + 1] - pooled[4 * k + 1]);
        o.z = g * (y[4 * k + 2] - pooled[4 * k + 2]);
        o.w = g * (y[4 * k + 3] - pooled[4 * k + 3]);
        dout4[k] = o;
    }
}

// ---------------- K2: per-b MFMA attention (t-loop over 9 contexts) ----------------
// All fragment arrays are row-major [row][K=32] bf16 so A-frags read
// &arr[(lane&15)*32 + quad*8] and B-frags read &arr[(lane&15)*32 + quad*8]
// per the m89/m120-verified 16x16x32 layouts.
__global__ __launch_bounds__(256, 4) void k2_attn(
    const float* __restrict__ x,
    const float* __restrict__ ws,        // wl05 @1024, rpm @1088
    const float* __restrict__ delta,
    const float* __restrict__ q_w, const float* __restrict__ q_b,
    const float* __restrict__ k_w, const float* __restrict__ k_b,
    const float* __restrict__ v_w, const float* __restrict__ v_b,
    const float* __restrict__ m_w, const float* __restrict__ m_b,
    const float* __restrict__ w_ctx,
    float* __restrict__ out)
{
    __shared__ __align__(16) short shF[1024];    // fused  [l 0..31][c 32]  rows 24..31 zero
    __shared__ __align__(16) short shW[3072];    // [n 0..95][k 32]  n: 0-31 q_w, 32-63 k_w, 64-95 v_w
    __shared__ __align__(16) short shQ[1024];    // q  [i][d32]
    __shared__ __align__(16) short shK[1024];    // k  [j][d32]
    __shared__ __align__(16) short shVT[1024];   // vT [c][j32]  cols j 24..31 zero
    __shared__ __align__(16) short shP[8192];    // P  [h][i 32][j 32]
    __shared__ __align__(16) short shXA[1024];   // x_att [l][c 32]
    __shared__ __align__(16) short shMW[1024];   // m_w [n=i][k=c]
    __shared__ float shMisc[672];
    // 0..383 rpm[8][48], 384..447 wl05, 448..511 wc, 512..607 bias(q,k,v), 608..639 bm, 640..671 delta

    int b = blockIdx.x;
    int tid = threadIdx.x;
    int wv = tid >> 6, lane = tid & 63, quad = lane >> 4, c16 = lane & 15;

    // ---- one-time staging ----
    for (int idx = tid; idx < 768; idx += 256) {      // q_w|k_w|v_w -> shW (direct row-major)
        const float* src = (idx < 256) ? q_w : (idx < 512) ? k_w : v_w;
        float4 v = ((const float4*)src)[idx & 255];
        short4 s4; s4.x = f2b(v.x); s4.y = f2b(v.y); s4.z = f2b(v.z); s4.w = f2b(v.w);
        *(short4*)&shW[idx * 4] = s4;
    }
    {
        float4 v = ((const float4*)m_w)[tid];          // 256 float4 = whole m_w
        short4 s4; s4.x = f2b(v.x); s4.y = f2b(v.y); s4.z = f2b(v.z); s4.w = f2b(v.w);
        *(short4*)&shMW[tid * 4] = s4;
    }
    for (int idx = tid; idx < 672; idx += 256) {
        float v;
        if (idx < 384)      v = ws[1088 + idx];
        else if (idx < 448) v = ws[1024 + idx - 384];
        else if (idx < 512) v = w_ctx[idx - 448];
        else if (idx < 544) v = q_b[idx - 512];
        else if (idx < 576) v = k_b[idx - 544];
        else if (idx < 608) v = v_b[idx - 576];
        else if (idx < 640) v = m_b[idx - 608];
        else                v = delta[(size_t)b * 32 + idx - 640];
        shMisc[idx] = v;
    }
    {   // zero pad rows of F and pad cols of vT
        shF[768 + tid] = 0;
        int n = tid >> 3, jj = 24 + (tid & 7);
        shVT[n * 32 + jj] = 0;
    }
    __syncthreads();

    for (int t = 0; t < TT; t++) {
        // ---- S1: load fused tile F[l][c] = x[b,c,t,l] + delta[c] ----
        if (tid < 192) {
            int c = tid / 6, k6 = tid % 6;
            float4 v = *(const float4*)(x + (size_t)b * (DD * NPOS) + (size_t)c * NPOS + t * LL + 4 * k6);
            float dl = shMisc[640 + c];
            int l0 = 4 * k6;
            shF[(l0 + 0) * 32 + c] = f2b(v.x + dl);
            shF[(l0 + 1) * 32 + c] = f2b(v.y + dl);
            shF[(l0 + 2) * 32 + c] = f2b(v.z + dl);
            shF[(l0 + 3) * 32 + c] = f2b(v.w + dl);
        }
        __syncthreads();

        // ---- S2/S3: projection mfma + per-head L2 norm + scatter to shQ/shK/shVT ----
        {
            int tm = wv >> 1;
            short8x afrag = *(short8x*)&shF[(16 * tm + c16) * 32 + quad * 8];
            #pragma unroll
            for (int s = 0; s < 3; s++) {
                int tn = (wv & 1) * 3 + s;
                short8x bfrag = *(short8x*)&shW[(16 * tn + c16) * 32 + quad * 8];
                float4x acc = {0.0f, 0.0f, 0.0f, 0.0f};
                acc = __builtin_amdgcn_mfma_f32_16x16x32_bf16(afrag, bfrag, acc, 0, 0, 0);
                int gc = 16 * tn + c16;                  // 0..95
                float bias = shMisc[512 + gc];
                #pragma unroll
                for (int e = 0; e < 4; e++) {
                    float d = acc[e] + bias;
                    float ss = d * d;
                    ss += __shfl_xor(ss, 1);
                    ss += __shfl_xor(ss, 2);             // sum over the 4 dims of this head
                    float val = d / fmaxf(sqrtf(ss), 1e-12f);
                    int gr = 16 * tm + quad * 4 + e;     // row (l), 24..31 pad
                    if (gc < 32)      shQ[gr * 32 + gc] = f2b(val);
                    else if (gc < 64) shK[gr * 32 + (gc - 32)] = f2b(val);
                    else if (gr < 24) shVT[(gc - 64) * 32 + gr] = f2b(val);  // transpose; keep pad cols zero
                }
            }
        }
        __syncthreads();

        // ---- S4: mixed logits (W_logit folded into K-frag scaling) + softmax + P store ----
        {
            short8x aq0 = *(short8x*)&shQ[c16 * 32 + quad * 8];
            short8x aq1 = *(short8x*)&shQ[(16 + c16) * 32 + quad * 8];
            short8x bk0 = *(short8x*)&shK[c16 * 32 + quad * 8];
            short8x bk1 = *(short8x*)&shK[(16 + c16) * 32 + quad * 8];
            #pragma unroll
            for (int hh = 0; hh < 2; hh++) {
                int H = 2 * wv + hh;
                float s0 = shMisc[384 + (2 * quad) * 8 + H];
                float s1 = shMisc[384 + (2 * quad + 1) * 8 + H];
                short8x bs0, bs1;
                #pragma unroll
                for (int j = 0; j < 8; j++) {
                    float sc = (j < 4) ? s0 : s1;
                    bs0[j] = f2b(b2f(bk0[j]) * sc);
                    bs1[j] = f2b(b2f(bk1[j]) * sc);
                }
                float4x l00 = {0,0,0,0}, l01 = {0,0,0,0}, l10 = {0,0,0,0}, l11 = {0,0,0,0};
                l00 = __builtin_amdgcn_mfma_f32_16x16x32_bf16(aq0, bs0, l00, 0, 0, 0);
                l01 = __builtin_amdgcn_mfma_f32_16x16x32_bf16(aq0, bs1, l01, 0, 0, 0);
                l10 = __builtin_amdgcn_mfma_f32_16x16x32_bf16(aq1, bs0, l10, 0, 0, 0);
                l11 = __builtin_amdgcn_mfma_f32_16x16x32_bf16(aq1, bs1, l11, 0, 0, 0);
                #pragma unroll
                for (int tmm = 0; tmm < 2; tmm++) {
                    float4x la = tmm ? l10 : l00;        // cols j = c16
                    float4x lb = tmm ? l11 : l01;        // cols j = 16 + c16
                    int j1 = 16 + c16;
                    #pragma unroll
                    for (int e = 0; e < 4; e++) {
                        int i = 16 * tmm + quad * 4 + e;
                        float v0 = la[e] + shMisc[H * 48 + min(i - c16 + 23, 47)];
                        float v1 = (j1 < 24) ? (lb[e] + shMisc[H * 48 + min(i - j1 + 23, 47)])
                                             : -1e30f;
                        float m = fmaxf(v0, v1);
                        m = fmaxf(m, __shfl_xor(m, 1));
                        m = fmaxf(m, __shfl_xor(m, 2));
                        m = fmaxf(m, __shfl_xor(m, 4));
                        m = fmaxf(m, __shfl_xor(m, 8));
                        float e0 = __expf(v0 - m);
                        float e1 = __expf(v1 - m);       // 0 for pad cols
                        float s = e0 + e1;
                        s += __shfl_xor(s, 1);
                        s += __shfl_xor(s, 2);
                        s += __shfl_xor(s, 4);
                        s += __shfl_xor(s, 8);
                        float inv = 1.0f / s;
                        shP[H * 1024 + i * 32 + c16]      = f2b(e0 * inv);
                        shP[H * 1024 + i * 32 + 16 + c16] = f2b(e1 * inv);
                    }
                }
            }
        }
        __syncthreads();

        // ---- S5: PV with W_ctx folded into P'-frag rebuild; head-masked V frags ----
        {
            int tmm = wv & 1, tnn = wv >> 1;
            short8x vfrag = *(short8x*)&shVT[(16 * tnn + c16) * 32 + quad * 8];
            short8x zfr = {0, 0, 0, 0, 0, 0, 0, 0};
            int hn = 4 * tnn + (c16 >> 2);               // head of this output column
            float4x pacc = {0.0f, 0.0f, 0.0f, 0.0f};
            #pragma unroll
            for (int hx = 0; hx < 4; hx++) {
                int H = 4 * tnn + hx;
                float accf[8] = {0, 0, 0, 0, 0, 0, 0, 0};
                #pragma unroll
                for (int h = 0; h < 8; h++) {
                    short8x ph = *(short8x*)&shP[h * 1024 + (16 * tmm + c16) * 32 + quad * 8];
                    float w = shMisc[448 + h * 8 + H];
                    #pragma unroll
                    for (int j = 0; j < 8; j++) accf[j] += w * b2f(ph[j]);
                }
                short8x pa;
                #pragma unroll
                for (int j = 0; j < 8; j++) pa[j] = f2b(accf[j]);
                short8x bmk = (hn == H) ? vfrag : zfr;
                pacc = __builtin_amdgcn_mfma_f32_16x16x32_bf16(pa, bmk, pacc, 0, 0, 0);
            }
            #pragma unroll
            for (int e = 0; e < 4; e++)
                shXA[(16 * tmm + quad * 4 + e) * 32 + 16 * tnn + c16] = f2b(pacc[e]);
        }
        __syncthreads();

        // ---- S6: m_w projection + bias + global store ----
        {
            int tm6 = wv & 1, tn6 = wv >> 1;
            short8x axa = *(short8x*)&shXA[(16 * tm6 + c16) * 32 + quad * 8];
            short8x bmw = *(short8x*)&shMW[(16 * tn6 + c16) * 32 + quad * 8];
            float4x oacc = {0.0f, 0.0f, 0.0f, 0.0f};
            oacc = __builtin_amdgcn_mfma_f32_16x16x32_bf16(axa, bmw, oacc, 0, 0, 0);
            int oc = 16 * tn6 + c16;
            int r0 = 16 * tm6 + quad * 4;
            if (r0 < 24) {
                float bmv = shMisc[608 + oc];
                float4 o;
                o.x = oacc[0] + bmv; o.y = oacc[1] + bmv;
                o.z = oacc[2] + bmv; o.w = oacc[3] + bmv;
                *(float4*)(out + (size_t)b * (DD * NPOS) + (size_t)oc * NPOS + t * LL + r0) = o;
            }
        }
        __syncthreads();
    }
}

// ---------------- K3: prediction branch ----------------
__global__ __launch_bounds__(256) void k3_pred(
    const float* __restrict__ pre_prompt,
    const float* __restrict__ conv_w, const float* __restrict__ conv_b,
    const float* __restrict__ p_w, const float* __restrict__ p_b,
    float* __restrict__ out)
{
    __shared__ float conf[DD * NPOS];            // 6912 floats
    __shared__ __hip_bfloat16 cwh[DD * 292];     // conv_w, per-co stride 292 (288 used)
    __shared__ float pbuff[DD * 25];             // [co][l] stride 25
    __shared__ __hip_bfloat16 pwh[576];
    __shared__ float pbv[24], cbv[32];
    int b = blockIdx.x, tid = threadIdx.x;

    const float4* o4 = (const float4*)(out + (size_t)b * (DD * NPOS));
    for (int idx = tid; idx < 1728; idx += 256) {
        int flat = idx * 4;
        int t = (flat % NPOS) / LL;              // uniform within the float4
        float4 v;
        if (t < 8) {
            v = o4[idx];
        } else {
            int c = flat / NPOS, l = flat % LL;  // 192 % 24 == 0
            v = ((const float4*)pre_prompt)[(c * LL + l) >> 2];
        }
        conf[flat + 0] = v.x; conf[flat + 1] = v.y; conf[flat + 2] = v.z; conf[flat + 3] = v.w;
    }
    for (int idx = tid; idx < 2304; idx += 256) {
        float4 v = ((const float4*)conv_w)[idx];
        int flat = idx * 4;
        float vv[4] = {v.x, v.y, v.z, v.w};
        #pragma unroll
        for (int e = 0; e < 4; e++) {
            int f = flat + e;
            int co = f / 288, r = f - co * 288;
            cwh[co * 292 + r] = __float2bfloat16(vv[e]);
        }
    }
    for (int idx = tid; idx < 144; idx += 256) {
        float4 v = ((const float4*)p_w)[idx];
        pwh[idx * 4 + 0] = __float2bfloat16(v.x);
        pwh[idx * 4 + 1] = __float2bfloat16(v.y);
        pwh[idx * 4 + 2] = __float2bfloat16(v.z);
        pwh[idx * 4 + 3] = __float2bfloat16(v.w);
    }
    if (tid < 24) pbv[tid] = p_b[tid];
    if (tid >= 32 && tid < 64) cbv[tid - 32] = conv_b[tid - 32];
    __syncthreads();

    // conv over contexts: thread = (co, l-quad)
    if (tid < 192) {
        int co = tid / 6, ql = tid - co * 6;
        float cb = cbv[co];
        float4 acc = {cb, cb, cb, cb};
        for (int ci = 0; ci < 32; ci++) {
            #pragma unroll
            for (int tt = 0; tt < 9; tt++) {
                float w = __bfloat162float(cwh[co * 292 + ci * 9 + tt]);
                float4 v = *(const float4*)&conf[ci * NPOS + tt * LL + ql * 4];
                acc.x += w * v.x; acc.y += w * v.y; acc.z += w * v.z; acc.w += w * v.w;
            }
        }
        pbuff[co * 25 + 4 * ql + 0] = fmaxf(acc.x, 0.0f);
        pbuff[co * 25 + 4 * ql + 1] = fmaxf(acc.y, 0.0f);
        pbuff[co * 25 + 4 * ql + 2] = fmaxf(acc.z, 0.0f);
        pbuff[co * 25 + 4 * ql + 3] = fmaxf(acc.w, 0.0f);
    }
    __syncthreads();

    // token linear + subtraction into the t=8 plane
    if (tid < 192) {
        int c = tid / 6, ql = tid - c * 6;
        float4 acc = {pbv[4 * ql + 0], pbv[4 * ql + 1], pbv[4 * ql + 2], pbv[4 * ql + 3]};
        #pragma unroll
        for (int lp = 0; lp < 24; lp++) {
            float pv = pbuff[c * 25 + lp];
            acc.x += pv * __bfloat162float(pwh[(4 * ql + 0) * 24 + lp]);
            acc.y += pv * __bfloat162float(pwh[(4 * ql + 1) * 24 + lp]);
            acc.z += pv * __bfloat162float(pwh[(4 * ql + 2) * 24 + lp]);
            acc.w += pv * __bfloat162float(pwh[(4 * ql + 3) * 24 + lp]);
        }
        float4* op = (float4*)(out + (size_t)b * (DD * NPOS) + (size_t)c * NPOS + 8 * LL);
        float4 xa = op[ql];
        float4 r;
        r.x = xa.x - acc.x; r.y = xa.y - acc.y; r.z = xa.z - acc.z; r.w = xa.w - acc.w;
        op[ql] = r;
    }
}

extern "C" void kernel_launch(void* const* d_in, const int* in_sizes, int n_in,
                              void* d_out, int out_size, void* d_ws, size_t ws_size,
                              hipStream_t stream) {
    const float* x        = (const float*)d_in[0];
    const float* ln_g     = (const float*)d_in[1];
    const float* ln_b     = (const float*)d_in[2];
    const float* rp_w1    = (const float*)d_in[3];
    const float* rp_b1    = (const float*)d_in[4];
    const float* rp_w2    = (const float*)d_in[5];
    const float* rp_b2    = (const float*)d_in[6];
    const float* W_causal = (const float*)d_in[7];
    const float* mask_w   = (const float*)d_in[8];
    const float* mask_b   = (const float*)d_in[9];
    const float* val_w1   = (const float*)d_in[10];
    const float* val_b1   = (const float*)d_in[11];
    const float* val_w2   = (const float*)d_in[12];
    const float* val_b2   = (const float*)d_in[13];
    const float* fuse_g   = (const float*)d_in[14];
    const float* q_w      = (const float*)d_in[15];
    const float* q_b      = (const float*)d_in[16];
    const float* k_w      = (const float*)d_in[17];
    const float* k_b      = (const float*)d_in[18];
    const float* v_w      = (const float*)d_in[19];
    const float* v_b      = (const float*)d_in[20];
    const float* m_w      = (const float*)d_in[21];
    const float* m_b      = (const float*)d_in[22];
    const float* W_logit  = (const float*)d_in[23];
    const float* W_ctx    = (const float*)d_in[24];
    const float* rel_pb   = (const float*)d_in[25];
    const float* pre_pr   = (const float*)d_in[26];
    const float* conv_w   = (const float*)d_in[27];
    const float* conv_b   = (const float*)d_in[28];
    const float* p_w      = (const float*)d_in[29];
    const float* p_b      = (const float*)d_in[30];
    float* out = (float*)d_out;

    int B = in_sizes[0] / (DD * NPOS);

    float* ws = (float*)d_ws;
    float* sp = ws + 2048;            // B*32 sums, then overwritten with g*delta
    float* sq = sp + (size_t)B * 32;  // B*32 sum-of-squares

    hipLaunchKernelGGL(k0_prep, dim3(1), dim3(1024), 0, stream, W_causal, W_logit, rel_pb, ws);
    hipLaunchKernelGGL(k1a, dim3(B), dim3(256), 0, stream, x, sp, sq);
    hipLaunchKernelGGL(k1b, dim3(B / 64), dim3(64), 0, stream,
                       ln_g, ln_b, rp_w1, rp_b1, rp_w2, rp_b2,
                       mask_w, mask_b, val_w1, val_b1, val_w2, val_b2,
                       fuse_g, ws, sp, sq);
    hipLaunchKernelGGL(k2_attn, dim3(B), dim3(256), 0, stream,
                       x, ws, sp, q_w, q_b, k_w, k_b, v_w, v_b, m_w, m_b,
                       W_ctx, out);
    hipLaunchKernelGGL(k3_pred, dim3(B), dim3(256), 0, stream,
                       pre_pr, conv_w, conv_b, p_w, p_b, out);
}